// Round 12
// baseline (228.135 us; speedup 1.0000x reference)
//
#include <hip/hip_runtime.h>

typedef unsigned short u16;
typedef unsigned int   u32;
typedef float  f32x4  __attribute__((ext_vector_type(4)));
typedef short  s16x8  __attribute__((ext_vector_type(8)));
typedef __bf16 bf16x8 __attribute__((ext_vector_type(8)));

#define GAMMA_C 0.02f     // 1/(2*sigma^2), sigma=5
#define NSPLIT 16

__device__ __forceinline__ float bf2f(u16 h) {
  union { u32 u; float f; } c; c.u = ((u32)h) << 16; return c.f;
}
__device__ __forceinline__ u16 f2bf(float f) {
  union { float f; u32 u; } c; c.f = f;
  u32 u = c.u;
  return (u16)((u + 0x7fffu + ((u >> 16) & 1u)) >> 16);
}
__device__ __forceinline__ f32x4 mfma16(s16x8 a, s16x8 b, f32x4 c) {
  union { s16x8 s; bf16x8 b; } ua, ub; ua.s = a; ub.s = b;
  return __builtin_amdgcn_mfma_f32_16x16x32_bf16(ua.b, ub.b, c, 0, 0, 0);
}
__device__ __forceinline__ void gload_lds16(const void* g, void* l) {
  __builtin_amdgcn_global_load_lds(
      (__attribute__((address_space(1))) const void*)g,
      (__attribute__((address_space(3))) void*)l, 16, 0, 0);
}

// -- f32 -> bf16 casts (y1, y2, W1, W2) + zero ZBUF (psum/psumsq/lacc/wacc/sacc/cnt) -
__global__ __launch_bounds__(256)
void castall(const float* __restrict__ y1, const float* __restrict__ y2,
             const float* __restrict__ W1, const float* __restrict__ W2,
             u16* __restrict__ Ybf, u16* __restrict__ W1bf,
             u16* __restrict__ W2bf, float* __restrict__ zbuf) {
  int b = blockIdx.x;
  if (b >= 10368) {                    // zero 132KB (33 blocks x 4KB)
    int i = ((b - 10368) * 256 + threadIdx.x) * 4;
    *(float4*)(zbuf + i) = make_float4(0.f, 0.f, 0.f, 0.f);
    return;
  }
  const float* src; u16* dst; int off;
  if (b < 4096)       { src = y1; dst = Ybf;           off = b; }
  else if (b < 8192)  { src = y2; dst = Ybf + 8388608; off = b - 4096; }
  else if (b < 10240) { src = W1; dst = W1bf;          off = b - 8192; }
  else                { src = W2; dst = W2bf;          off = b - 10240; }
  int idx = (off * 256 + threadIdx.x) * 8;
  float4 a = *(const float4*)(src + idx);
  float4 c = *(const float4*)(src + idx + 4);
  int4 ov; u16* op = (u16*)&ov;
  op[0]=f2bf(a.x); op[1]=f2bf(a.y); op[2]=f2bf(a.z); op[3]=f2bf(a.w);
  op[4]=f2bf(c.x); op[5]=f2bf(c.y); op[6]=f2bf(c.z); op[7]=f2bf(c.w);
  *(int4*)(dst + idx) = ov;
}

// ============ gemm1: 256x256, BK=64, 8 waves, 4-phase (round-7 proven, 904 TF) ====
#define SWZ1(row) (((row) & 7) << 4)
#define BAR() __builtin_amdgcn_s_barrier()
#define VMW0() asm volatile("s_waitcnt vmcnt(0)" ::: "memory")

#define STAGE_T(BUF, KT) do {                                                      \
  _Pragma("unroll")                                                                \
  for (int c_ = 0; c_ < 4; ++c_) {                                                 \
    int e_ = tid + c_*512; int row_ = e_ >> 3; int b_ = (e_ & 7) * 16;             \
    int bs_ = b_ ^ SWZ1(row_);                                                     \
    gload_lds16((const char*)A + (size_t)(tm+row_)*4096 + (KT)*2 + bs_,            \
                (char*)&As[BUF][0] + (c_*512 + wave*64)*16);                       \
    gload_lds16((const char*)B + (size_t)(tn+row_)*4096 + (KT)*2 + bs_,            \
                (char*)&Bs[BUF][0] + (c_*512 + wave*64)*16);                       \
  }                                                                                \
} while (0)

#define LDA(DST, BUF, MH) do {                                                     \
  _Pragma("unroll")                                                                \
  for (int m_ = 0; m_ < 4; ++m_)                                                   \
    _Pragma("unroll")                                                              \
    for (int kk_ = 0; kk_ < 2; ++kk_) {                                            \
      int arow_ = wr*16 + ((MH)*4 + m_)*32 + r16;                                  \
      DST[m_*2 + kk_] = *(const s16x8*)((const char*)&As[BUF][0] + arow_*128 +     \
                          ((kk_*64 + g*16) ^ SWZ1(arow_)));                        \
    }                                                                              \
} while (0)

#define LDB(DST, BUF, NH) do {                                                     \
  _Pragma("unroll")                                                                \
  for (int n_ = 0; n_ < 2; ++n_)                                                   \
    _Pragma("unroll")                                                              \
    for (int kk_ = 0; kk_ < 2; ++kk_) {                                            \
      int brow_ = wc*16 + ((NH)*2 + n_)*64 + r16;                                  \
      DST[n_*2 + kk_] = *(const s16x8*)((const char*)&Bs[BUF][0] + brow_*128 +     \
                          ((kk_*64 + g*16) ^ SWZ1(brow_)));                        \
    }                                                                               \
} while (0)

#define MMQ(AF, MH, NH) do {                                                       \
  __builtin_amdgcn_s_setprio(1);                                                   \
  _Pragma("unroll")                                                                \
  for (int m_ = 0; m_ < 4; ++m_)                                                   \
    _Pragma("unroll")                                                              \
    for (int n_ = 0; n_ < 2; ++n_)                                                 \
      _Pragma("unroll")                                                            \
      for (int kk_ = 0; kk_ < 2; ++kk_)                                            \
        acc[(MH)*4 + m_][(NH)*2 + n_] =                                            \
          mfma16(AF[m_*2 + kk_], bv[n_*2 + kk_], acc[(MH)*4 + m_][(NH)*2 + n_]);   \
  __builtin_amdgcn_s_setprio(0);                                                   \
} while (0)

__global__ __launch_bounds__(512, 2)
void gemm1(const u16* __restrict__ A, const u16* __restrict__ B,
           u16* __restrict__ C, float* __restrict__ psum, float* __restrict__ psumsq)
{
  __shared__ u16 As[2][256*64];
  __shared__ u16 Bs[2][256*64];
  const int tid = threadIdx.x;
  const int lane = tid & 63, wave = tid >> 6;   // 8 waves
  const int wr = wave >> 2, wc = wave & 3;      // 2 x 4
  const int g = lane >> 4, r16 = lane & 15;
  const int lin = blockIdx.x;                   // 256 blocks, 256 % 8 == 0
  const int wgid = (lin & 7) * 32 + (lin >> 3); // XCD owns 32 contiguous wgids
  const int by = wgid >> 3, bx = wgid & 7;
  const int tm = by * 256, tn = bx * 256;

  f32x4 acc[8][4] = {};
  s16x8 af0[8], af1[8], bv[4];

  STAGE_T(0, 0);
  VMW0(); BAR();

  for (int t = 0; t < 32; ++t) {
    const int cur = t & 1, nxt = cur ^ 1;
    const int ktn = (t + 1) * 64;
    // P1: quadrant (mh0, nh0); stage whole next tile
    LDA(af0, cur, 0);  LDB(bv, cur, 0);
    if (t < 31) STAGE_T(nxt, ktn);
    BAR();  MMQ(af0, 0, 0);  BAR();
    // P2: (mh1, nh0)
    LDA(af1, cur, 1);
    BAR();  MMQ(af1, 1, 0);  BAR();
    // P3: (mh1, nh1)
    LDB(bv, cur, 1);
    BAR();  MMQ(af1, 1, 1);  BAR();
    // P4: (mh0, nh1); confirm next tile (loads are 3 phases old)
    if (t < 31) VMW0();
    BAR();  MMQ(af0, 0, 1);  BAR();
  }

  // epilogue: C store (bf16); C/D frag: col=lane&15, row=(lane>>4)*4+reg
  #pragma unroll
  for (int m = 0; m < 8; ++m)
    #pragma unroll
    for (int n = 0; n < 4; ++n)
      #pragma unroll
      for (int r = 0; r < 4; ++r) {
        int row = tm + wr*16 + m*32 + g*4 + r;
        int col = tn + wc*16 + n*64 + r16;
        C[(size_t)row*2048 + col] = f2bf(acc[m][n][r]);
      }

  // BN column partials over this block's 256 rows -> one atomicAdd per column
  __syncthreads();
  float* sred  = (float*)&As[0][0];   // [2][256]
  float* ssred = sred + 512;
  #pragma unroll
  for (int n = 0; n < 4; ++n) {
    float s = 0.f, ss = 0.f;
    #pragma unroll
    for (int m = 0; m < 8; ++m)
      #pragma unroll
      for (int r = 0; r < 4; ++r) { float v = acc[m][n][r]; s += v; ss = fmaf(v, v, ss); }
    s  += __shfl_xor(s, 16);  s  += __shfl_xor(s, 32);
    ss += __shfl_xor(ss, 16); ss += __shfl_xor(ss, 32);
    if (g == 0) {
      int lc = wc*16 + n*64 + r16;
      sred [wr*256 + lc] = s;
      ssred[wr*256 + lc] = ss;
    }
  }
  __syncthreads();
  if (tid < 256) {
    int half = tm >> 12;
    atomicAdd(&psum  [half*2048 + tn + tid], sred [tid] + sred [256 + tid]);
    atomicAdd(&psumsq[half*2048 + tn + tid], ssred[tid] + ssred[256 + tid]);
  }
}

// ======= gemm2f: Z-partials = relu(BN(H)) * W2^T, split-K, bf16 partial out; ======
// inline BN finalize; LAST split block per row-panel fuses the 8-partial sum +
// per-row L2 normalize (device counter; castall re-zeroes counters each call).
__global__ __launch_bounds__(256)
void gemm2f(const u16* __restrict__ Hraw, const u16* __restrict__ W2bf,
            const float* __restrict__ psum, const float* __restrict__ psumsq,
            const float* __restrict__ gam, const float* __restrict__ bet,
            u16* __restrict__ Zp, u16* __restrict__ Zb, int* __restrict__ cnt,
            int kLen)
{
  __shared__ u16 As[128*64];
  __shared__ u16 Bs[128*64];
  __shared__ float sLDS[256], bLDS[256];
  __shared__ int lastFlag;
  const int tid = threadIdx.x;
  const int lane = tid & 63, wave = tid >> 6;
  const int wr = wave >> 1, wc = wave & 1;
  const int g = lane >> 4, r16 = lane & 15;
  const int tm = blockIdx.y * 128, tn = blockIdx.x * 128;
  const int kOff = blockIdx.z * kLen;
  const int half = tm >> 12;

  {                                         // inline BN finalize for [kOff, kOff+256)
    int c = half*2048 + kOff + tid;
    float mu  = psum[c] * (1.f/4096.f);
    float var = fmaxf(psumsq[c] * (1.f/4096.f) - mu*mu, 0.f);
    float sc = gam[kOff + tid] * rsqrtf(var + 1e-5f);
    sLDS[tid] = sc;
    bLDS[tid] = bet[kOff + tid] - mu * sc;
  }
  __syncthreads();

  f32x4 acc[4][4] = {};

  for (int kt = kOff; kt < kOff + kLen; kt += 64) {
    #pragma unroll
    for (int c = 0; c < 4; ++c) {           // B: gload_lds, pre-swizzled source
      int ld = (tid + c*256) * 16;
      int row = ld >> 7, b = ld & 127;
      int bs = b ^ ((row & 7) << 4);
      gload_lds16((const char*)W2bf + (size_t)(tn+row)*4096 + (kt*2 + bs),
                  (char*)Bs + (wave*64 + c*256)*16);
    }
    #pragma unroll
    for (int c = 0; c < 4; ++c) {           // A: reg-stage + BN + ReLU
      int ld = (tid + c*256) * 16;
      int row = ld >> 7, b = ld & 127;
      int kg = (kt - kOff) + (b >> 1);      // [0,256) LDS-local
      int4 hv = *(const int4*)((const char*)Hraw + (size_t)(tm+row)*4096 + kt*2 + b);
      f32x4 s0 = *(const f32x4*)(sLDS + kg), s1 = *(const f32x4*)(sLDS + kg + 4);
      f32x4 b0 = *(const f32x4*)(bLDS + kg), b1 = *(const f32x4*)(bLDS + kg + 4);
      u16* hp = (u16*)&hv;
      int4 ov; u16* op = (u16*)&ov;
      #pragma unroll
      for (int j = 0; j < 4; ++j)
        op[j]   = f2bf(fmaxf(fmaf(bf2f(hp[j]),   s0[j], b0[j]), 0.f));
      #pragma unroll
      for (int j = 0; j < 4; ++j)
        op[4+j] = f2bf(fmaxf(fmaf(bf2f(hp[4+j]), s1[j], b1[j]), 0.f));
      *(int4*)((char*)As + row*128 + (b ^ ((row & 7) << 4))) = ov;
    }
    __syncthreads();
    #pragma unroll
    for (int kk = 0; kk < 2; ++kk) {
      s16x8 af[4], bv[4];
      #pragma unroll
      for (int m = 0; m < 4; ++m) {
        int row = wr*64 + m*16 + r16;
        af[m] = *(const s16x8*)((const char*)As + row*128 +
                                ((kk*64 + g*16) ^ ((row & 7) << 4)));
      }
      #pragma unroll
      for (int n = 0; n < 4; ++n) {
        int row = wc*64 + n*16 + r16;
        bv[n] = *(const s16x8*)((const char*)Bs + row*128 +
                                ((kk*64 + g*16) ^ ((row & 7) << 4)));
      }
      #pragma unroll
      for (int m = 0; m < 4; ++m)
        #pragma unroll
        for (int n = 0; n < 4; ++n)
          acc[m][n] = mfma16(af[m], bv[n], acc[m][n]);
    }
    __syncthreads();
  }

  u16* Cfo = Zp + (size_t)blockIdx.z * (8192*128);
  #pragma unroll
  for (int m = 0; m < 4; ++m)
    #pragma unroll
    for (int n = 0; n < 4; ++n)
      #pragma unroll
      for (int r = 0; r < 4; ++r) {
        int row = tm + wr*64 + m*16 + g*4 + r;
        int col = tn + wc*64 + n*16 + r16;
        Cfo[(size_t)row*128 + col] = f2bf(acc[m][n][r]);
      }

  // last-split-done: fuse partial-sum + L2 normalize for rows [tm, tm+128)
  __threadfence();
  if (tid == 0) lastFlag = (atomicAdd(&cnt[blockIdx.y], 1) == 7);
  __syncthreads();
  if (lastFlag) {
    #pragma unroll
    for (int rr = 0; rr < 8; ++rr) {
      int row = tm + rr*16 + (tid >> 4);
      int l16 = tid & 15;
      size_t off = (size_t)row*128 + l16*8;
      f32x4 v0 = {0.f,0.f,0.f,0.f}, v1 = {0.f,0.f,0.f,0.f};
      #pragma unroll
      for (int s = 0; s < 8; ++s) {
        int4 pv = *(const int4*)(Zp + (size_t)s*1048576 + off);
        const u16* pp = (const u16*)&pv;
        v0[0] += bf2f(pp[0]); v0[1] += bf2f(pp[1]); v0[2] += bf2f(pp[2]); v0[3] += bf2f(pp[3]);
        v1[0] += bf2f(pp[4]); v1[1] += bf2f(pp[5]); v1[2] += bf2f(pp[6]); v1[3] += bf2f(pp[7]);
      }
      float ss = v0[0]*v0[0] + v0[1]*v0[1] + v0[2]*v0[2] + v0[3]*v0[3]
               + v1[0]*v1[0] + v1[1]*v1[1] + v1[2]*v1[2] + v1[3]*v1[3];
      #pragma unroll
      for (int o = 1; o < 16; o <<= 1) ss += __shfl_xor(ss, o);
      float rs = rsqrtf(ss);
      rs = rs * (1.5f - 0.5f * ss * rs * rs);
      int4 ov; u16* op = (u16*)&ov;
      op[0]=f2bf(v0[0]*rs); op[1]=f2bf(v0[1]*rs); op[2]=f2bf(v0[2]*rs); op[3]=f2bf(v0[3]*rs);
      op[4]=f2bf(v1[0]*rs); op[5]=f2bf(v1[1]*rs); op[6]=f2bf(v1[2]*rs); op[7]=f2bf(v1[3]*rs);
      *(int4*)((char*)Zb + off*2) = ov;
    }
  }
}

// --- fused sim + fixed-max LSE + weighted score + weight-sum (128 rows/block) ------
#define LOAD_COL(DC, DL, IT) do {                                                  \
  int jr_ = colBase + (IT)*16;                                                     \
  const char* zcp_ = (const char*)Zb + (size_t)(jr_ + r16)*256 + g*16;             \
  DC[0] = *(const s16x8*)(zcp_);        DC[1] = *(const s16x8*)(zcp_ +  64);       \
  DC[2] = *(const s16x8*)(zcp_ + 128);  DC[3] = *(const s16x8*)(zcp_ + 192);       \
  DL = *(const f32x4*)(labels + ((jr_ & 4095) + g*4));                             \
} while (0)

#define LBODY(CC, CL, IT) do {                                                     \
  int jrow_ = colBase + (IT)*16;                                                   \
  f32x4 aacc[8] = {};                                                              \
  _Pragma("unroll")                                                                \
  for (int kk = 0; kk < 4; ++kk) {                                                 \
    _Pragma("unroll")                                                              \
    for (int is = 0; is < 8; ++is)                                                 \
      aacc[is] = mfma16(CC[kk], zr[is][kk], aacc[is]);                             \
  }                                                                                \
  _Pragma("unroll")                                                                \
  for (int r = 0; r < 4; ++r) {                                                    \
    int j = jrow_ + g*4 + r;                                                       \
    _Pragma("unroll")                                                              \
    for (int is = 0; is < 8; ++is) {                                               \
      float d = aacc[is][r];                                                       \
      bool diag = (rowBase + is*16 + r16) == j;                                    \
      float e  = __expf(fmaf(d, 10.f, -10.f));                                     \
      float dl = li[is] - CL[r];                                                   \
      float w  = __expf(-GAMMA_C * dl * dl);                                       \
      e = diag ? 0.f : e;                                                          \
      w = diag ? 0.f : w;                                                          \
      l[is] += e;                                                                  \
      wS[is] += w;                                                                 \
      wA[is] = fmaf(w, d, wA[is]);                                                 \
    }                                                                              \
  }                                                                                \
} while (0)

__global__ __launch_bounds__(64)
void lossk(const u16* __restrict__ Zb, const float* __restrict__ labels,
           float* __restrict__ lacc, float* __restrict__ wacc,
           float* __restrict__ sacc)
{
  const int lane = threadIdx.x & 63;
  const int g = lane >> 4, r16 = lane & 15;
  const int split = blockIdx.x;
  const int rowBase = blockIdx.y * 128;
  const int colBase = split * 512;

  s16x8 zr[8][4];
  float li[8];
  #pragma unroll
  for (int is = 0; is < 8; ++is) {
    int i = rowBase + is*16 + r16;
    li[is] = labels[i & 4095];
    #pragma unroll
    for (int kk = 0; kk < 4; ++kk)
      zr[is][kk] = *(const s16x8*)((const char*)Zb + (size_t)i*256 + kk*64 + g*16);
  }

  float l[8]  = {};
  float wA[8] = {};
  float wS[8] = {};

  s16x8 cA[4], cB[4];
  f32x4 lA, lB;
  LOAD_COL(cA, lA, 0);
  for (int it = 0; it < 32; it += 2) {      // 32 col-tiles of 16
    LOAD_COL(cB, lB, it + 1);
    LBODY(cA, lA, it);
    if (it + 2 < 32) LOAD_COL(cA, lA, it + 2);
    LBODY(cB, lB, it + 1);
  }

  #pragma unroll
  for (int is = 0; is < 8; ++is) {
    float lv = l[is], wv = wA[is], sv = wS[is];
    lv += __shfl_xor(lv, 16); lv += __shfl_xor(lv, 32);
    wv += __shfl_xor(wv, 16); wv += __shfl_xor(wv, 32);
    sv += __shfl_xor(sv, 16); sv += __shfl_xor(sv, 32);
    if (g == 0) {
      int i = rowBase + is*16 + r16;
      atomicAdd(&lacc[i], lv);
      atomicAdd(&wacc[i], wv);
      atomicAdd(&sacc[i], sv);
    }
  }
}

// ---------------- per-row loss + final reduce ----------------
__global__ __launch_bounds__(256)
void finalk(const float* __restrict__ lacc, const float* __restrict__ wacc,
            const float* __restrict__ sacc, float* __restrict__ out)
{
  __shared__ float red[256];
  float a = 0.f;
  for (int i = threadIdx.x; i < 8192; i += 256)
    a += wacc[i] * 10.f / sacc[i] - (10.f + logf(lacc[i]));
  red[threadIdx.x] = a;
  __syncthreads();
  for (int off = 128; off > 0; off >>= 1) {
    if (threadIdx.x < off) red[threadIdx.x] += red[threadIdx.x + off];
    __syncthreads();
  }
  if (threadIdx.x == 0) out[0] = -red[0] * (1.f/4096.f);
}

extern "C" void kernel_launch(void* const* d_in, const int* in_sizes, int n_in,
                              void* d_out, int out_size, void* d_ws, size_t ws_size,
                              hipStream_t stream) {
  const float* y1     = (const float*)d_in[0];
  const float* y2     = (const float*)d_in[1];
  const float* labels = (const float*)d_in[2];
  const float* W1     = (const float*)d_in[3];
  const float* bng    = (const float*)d_in[4];
  const float* bnb    = (const float*)d_in[5];
  const float* W2     = (const float*)d_in[6];
  float* out = (float*)d_out;
  char* ws = (char*)d_ws;

  // layout (peak 76,156,928 B):
  u16*   Ybf    = (u16*)(ws);                    // [0, 32M)      dead after gemm1
  u16*   W1bf   = (u16*)(ws + 33554432);         // [32M, 40M)    dead after gemm1
  float* zbuf   = (float*)(ws + 41943040);       // 132KB ZBUF (zeroed by castall)
  float* psum   = (float*)(ws + 41943040);       //   16KB
  float* psumsq = (float*)(ws + 41959424);       //   16KB
  float* lacc   = (float*)(ws + 41975808);       //   32KB
  float* wacc   = (float*)(ws + 42008576);       //   32KB
  float* sacc   = (float*)(ws + 42041344);       //   32KB
  int*   cnt    = (int*)  (ws + 42074112);       //    4KB -> ends 42,078,208
  u16*   W2bf   = (u16*)(ws + 42078208);         // 512KB -> ends 42,602,496
  u16*   Hraw   = (u16*)(ws + 42602496);         // 32MB  -> ends 76,156,928
  // post-gemm1 overlays (dead Ybf/W1bf):
  u16*   Zp     = (u16*)(ws + 32768);            // 16MB [8][8192][128] bf16
  u16*   Zbf    = (u16*)(ws + 33587200);         // 2MB -> ends 35,684,352

  castall<<<10401, 256, 0, stream>>>(y1, y2, W1, W2, Ybf, W1bf, W2bf, zbuf);
  gemm1<<<256, 512, 0, stream>>>(Ybf, W1bf, Hraw, psum, psumsq);
  gemm2f<<<dim3(1,64,8), 256, 0, stream>>>(Hraw, W2bf, psum, psumsq, bng, bnb,
                                           Zp, Zbf, cnt, 256);
  lossk<<<dim3(NSPLIT, 64), 64, 0, stream>>>(Zbf, labels, lacc, wacc, sacc);
  finalk<<<1, 256, 0, stream>>>(lacc, wacc, sacc, out);
}

// Round 13
// 153.368 us; speedup vs baseline: 1.4875x; 1.4875x over previous
//
#include <hip/hip_runtime.h>

typedef unsigned short u16;
typedef unsigned int   u32;
typedef float  f32x4  __attribute__((ext_vector_type(4)));
typedef short  s16x8  __attribute__((ext_vector_type(8)));
typedef __bf16 bf16x8 __attribute__((ext_vector_type(8)));

#define GAMMA_C 0.02f     // 1/(2*sigma^2), sigma=5
#define NSPLIT 16

__device__ __forceinline__ float bf2f(u16 h) {
  union { u32 u; float f; } c; c.u = ((u32)h) << 16; return c.f;
}
__device__ __forceinline__ u16 f2bf(float f) {
  union { float f; u32 u; } c; c.f = f;
  u32 u = c.u;
  return (u16)((u + 0x7fffu + ((u >> 16) & 1u)) >> 16);
}
__device__ __forceinline__ f32x4 mfma16(s16x8 a, s16x8 b, f32x4 c) {
  union { s16x8 s; bf16x8 b; } ua, ub; ua.s = a; ub.s = b;
  return __builtin_amdgcn_mfma_f32_16x16x32_bf16(ua.b, ub.b, c, 0, 0, 0);
}
__device__ __forceinline__ void gload_lds16(const void* g, void* l) {
  __builtin_amdgcn_global_load_lds(
      (__attribute__((address_space(1))) const void*)g,
      (__attribute__((address_space(3))) void*)l, 16, 0, 0);
}

// -- f32 -> bf16 casts (y1, y2, W1, W2) + zero ZBUF (psum/psumsq/lacc/wacc/sacc) ----
__global__ __launch_bounds__(256)
void castall(const float* __restrict__ y1, const float* __restrict__ y2,
             const float* __restrict__ W1, const float* __restrict__ W2,
             u16* __restrict__ Ybf, u16* __restrict__ W1bf,
             u16* __restrict__ W2bf, float* __restrict__ zbuf) {
  int b = blockIdx.x;
  if (b >= 10368) {                    // zero 128KB (32 blocks x 4KB)
    int i = ((b - 10368) * 256 + threadIdx.x) * 4;
    *(float4*)(zbuf + i) = make_float4(0.f, 0.f, 0.f, 0.f);
    return;
  }
  const float* src; u16* dst; int off;
  if (b < 4096)       { src = y1; dst = Ybf;           off = b; }
  else if (b < 8192)  { src = y2; dst = Ybf + 8388608; off = b - 4096; }
  else if (b < 10240) { src = W1; dst = W1bf;          off = b - 8192; }
  else                { src = W2; dst = W2bf;          off = b - 10240; }
  int idx = (off * 256 + threadIdx.x) * 8;
  float4 a = *(const float4*)(src + idx);
  float4 c = *(const float4*)(src + idx + 4);
  int4 ov; u16* op = (u16*)&ov;
  op[0]=f2bf(a.x); op[1]=f2bf(a.y); op[2]=f2bf(a.z); op[3]=f2bf(a.w);
  op[4]=f2bf(c.x); op[5]=f2bf(c.y); op[6]=f2bf(c.z); op[7]=f2bf(c.w);
  *(int4*)(dst + idx) = ov;
}

// ===== gemm1 v5: r7 schedule + T4 counted-vmcnt (quarters spread, never drain) =====
// Quarter Qc = {A rows c*64..c*64+63, B same} = 2 loads/thread. Steady state:
// P1 stages Q3(t+1), VMW(6) retires Q4(t); P2 stages Q4(t+1); P3 stages Q1(t+2)
// into cur (rows dead since P1); P4 stages Q2(t+2), VMW(6) retires Q1-Q3(t+1).
#define SWZ1(row) (((row) & 7) << 4)
#define BAR() __builtin_amdgcn_s_barrier()
#define VMW0() asm volatile("s_waitcnt vmcnt(0)" ::: "memory")
#define VMW6() asm volatile("s_waitcnt vmcnt(6)" ::: "memory")

#define STAGE_Q(BUF, KT, CQ) do {                                                  \
  int e_ = tid + (CQ)*512; int row_ = e_ >> 3; int b_ = (e_ & 7) * 16;             \
  int bs_ = b_ ^ SWZ1(row_);                                                       \
  gload_lds16((const char*)A + (size_t)(tm+row_)*4096 + (KT)*2 + bs_,              \
              (char*)&As[BUF][0] + ((CQ)*512 + wave*64)*16);                       \
  gload_lds16((const char*)B + (size_t)(tn+row_)*4096 + (KT)*2 + bs_,              \
              (char*)&Bs[BUF][0] + ((CQ)*512 + wave*64)*16);                       \
} while (0)

#define LDA(DST, BUF, MH) do {                                                     \
  _Pragma("unroll")                                                                \
  for (int m_ = 0; m_ < 4; ++m_)                                                   \
    _Pragma("unroll")                                                              \
    for (int kk_ = 0; kk_ < 2; ++kk_) {                                            \
      int arow_ = wr*16 + ((MH)*4 + m_)*32 + r16;                                  \
      DST[m_*2 + kk_] = *(const s16x8*)((const char*)&As[BUF][0] + arow_*128 +     \
                          ((kk_*64 + g*16) ^ SWZ1(arow_)));                        \
    }                                                                              \
} while (0)

#define LDB(DST, BUF, NH) do {                                                     \
  _Pragma("unroll")                                                                \
  for (int n_ = 0; n_ < 2; ++n_)                                                   \
    _Pragma("unroll")                                                              \
    for (int kk_ = 0; kk_ < 2; ++kk_) {                                            \
      int brow_ = wc*16 + ((NH)*2 + n_)*64 + r16;                                  \
      DST[n_*2 + kk_] = *(const s16x8*)((const char*)&Bs[BUF][0] + brow_*128 +     \
                          ((kk_*64 + g*16) ^ SWZ1(brow_)));                        \
    }                                                                              \
} while (0)

#define MMQ(AF, MH, NH) do {                                                       \
  __builtin_amdgcn_s_setprio(1);                                                   \
  _Pragma("unroll")                                                                \
  for (int m_ = 0; m_ < 4; ++m_)                                                   \
    _Pragma("unroll")                                                              \
    for (int n_ = 0; n_ < 2; ++n_)                                                 \
      _Pragma("unroll")                                                            \
      for (int kk_ = 0; kk_ < 2; ++kk_)                                            \
        acc[(MH)*4 + m_][(NH)*2 + n_] =                                            \
          mfma16(AF[m_*2 + kk_], bv[n_*2 + kk_], acc[(MH)*4 + m_][(NH)*2 + n_]);   \
  __builtin_amdgcn_s_setprio(0);                                                   \
} while (0)

__global__ __launch_bounds__(512, 2)
void gemm1(const u16* __restrict__ A, const u16* __restrict__ B,
           u16* __restrict__ C, float* __restrict__ psum, float* __restrict__ psumsq)
{
  __shared__ u16 As[2][256*64];
  __shared__ u16 Bs[2][256*64];
  const int tid = threadIdx.x;
  const int lane = tid & 63, wave = tid >> 6;   // 8 waves
  const int wr = wave >> 2, wc = wave & 3;      // 2 x 4
  const int g = lane >> 4, r16 = lane & 15;
  const int lin = blockIdx.x;                   // 256 blocks, 256 % 8 == 0
  const int wgid = (lin & 7) * 32 + (lin >> 3); // XCD owns 32 contiguous wgids
  const int by = wgid >> 3, bx = wgid & 7;
  const int tm = by * 256, tn = bx * 256;

  f32x4 acc[8][4] = {};
  s16x8 af0[8], af1[8], bv[4];

  // prologue: tile0 full (8 loads) + Q1,Q2 of tile1 (4 loads); retire tile0
  STAGE_Q(0, 0, 0); STAGE_Q(0, 0, 1); STAGE_Q(0, 0, 2); STAGE_Q(0, 0, 3);
  STAGE_Q(1, 64, 0); STAGE_Q(1, 64, 1);
  asm volatile("s_waitcnt vmcnt(4)" ::: "memory");
  BAR();

  for (int t = 0; t < 32; ++t) {
    const int cur = t & 1, nxt = cur ^ 1;
    const int ktn = (t + 1) * 64, ktn2 = (t + 2) * 64;
    // P1: read q1 frags (Q1,Q2 cur: confirmed at P4(t-1)); stage Q3(t+1); retire Q4(t)
    LDA(af0, cur, 0);  LDB(bv, cur, 0);
    if (t < 31) { STAGE_Q(nxt, ktn, 2); VMW6(); }
    BAR();  MMQ(af0, 0, 0);  BAR();
    // P2: read q2 frags (Q3,Q4 cur confirmed); stage Q4(t+1)
    LDA(af1, cur, 1);
    if (t < 31) STAGE_Q(nxt, ktn, 3);
    BAR();  MMQ(af1, 1, 0);  BAR();
    // P3: read q3 frags; stage Q1(t+2) into cur (rows 0-63 dead since P1)
    LDB(bv, cur, 1);
    if (t < 30) STAGE_Q(cur, ktn2, 0);
    BAR();  MMQ(af1, 1, 1);  BAR();
    // P4: stage Q2(t+2); retire Q1-Q3(t+1) (t=30: full drain for tail)
    if (t < 30)      { STAGE_Q(cur, ktn2, 1); VMW6(); }
    else if (t == 30) VMW0();
    BAR();  MMQ(af0, 0, 1);  BAR();
  }

  // epilogue: C store (bf16); C/D frag: col=lane&15, row=(lane>>4)*4+reg
  #pragma unroll
  for (int m = 0; m < 8; ++m)
    #pragma unroll
    for (int n = 0; n < 4; ++n)
      #pragma unroll
      for (int r = 0; r < 4; ++r) {
        int row = tm + wr*16 + m*32 + g*4 + r;
        int col = tn + wc*16 + n*64 + r16;
        C[(size_t)row*2048 + col] = f2bf(acc[m][n][r]);
      }

  // BN column partials over this block's 256 rows -> one atomicAdd per column
  __syncthreads();
  float* sred  = (float*)&As[0][0];   // [2][256]
  float* ssred = sred + 512;
  #pragma unroll
  for (int n = 0; n < 4; ++n) {
    float s = 0.f, ss = 0.f;
    #pragma unroll
    for (int m = 0; m < 8; ++m)
      #pragma unroll
      for (int r = 0; r < 4; ++r) { float v = acc[m][n][r]; s += v; ss = fmaf(v, v, ss); }
    s  += __shfl_xor(s, 16);  s  += __shfl_xor(s, 32);
    ss += __shfl_xor(ss, 16); ss += __shfl_xor(ss, 32);
    if (g == 0) {
      int lc = wc*16 + n*64 + r16;
      sred [wr*256 + lc] = s;
      ssred[wr*256 + lc] = ss;
    }
  }
  __syncthreads();
  if (tid < 256) {
    int half = tm >> 12;
    atomicAdd(&psum  [half*2048 + tn + tid], sred [tid] + sred [256 + tid]);
    atomicAdd(&psumsq[half*2048 + tn + tid], ssred[tid] + ssred[256 + tid]);
  }
}

// ======= gemm2f: Z-partials = relu(BN(H)) * W2^T, split-K, bf16 partial out; ======
// inline BN finalize from psum/psumsq (r11 proven — NO fences, NO counters).
__global__ __launch_bounds__(256)
void gemm2f(const u16* __restrict__ Hraw, const u16* __restrict__ W2bf,
            const float* __restrict__ psum, const float* __restrict__ psumsq,
            const float* __restrict__ gam, const float* __restrict__ bet,
            u16* __restrict__ Zp, int kLen)
{
  __shared__ u16 As[128*64];
  __shared__ u16 Bs[128*64];
  __shared__ float sLDS[256], bLDS[256];
  const int tid = threadIdx.x;
  const int lane = tid & 63, wave = tid >> 6;
  const int wr = wave >> 1, wc = wave & 1;
  const int g = lane >> 4, r16 = lane & 15;
  const int tm = blockIdx.y * 128, tn = blockIdx.x * 128;
  const int kOff = blockIdx.z * kLen;
  const int half = tm >> 12;

  {                                         // inline BN finalize for [kOff, kOff+256)
    int c = half*2048 + kOff + tid;
    float mu  = psum[c] * (1.f/4096.f);
    float var = fmaxf(psumsq[c] * (1.f/4096.f) - mu*mu, 0.f);
    float sc = gam[kOff + tid] * rsqrtf(var + 1e-5f);
    sLDS[tid] = sc;
    bLDS[tid] = bet[kOff + tid] - mu * sc;
  }
  __syncthreads();

  f32x4 acc[4][4] = {};

  for (int kt = kOff; kt < kOff + kLen; kt += 64) {
    #pragma unroll
    for (int c = 0; c < 4; ++c) {           // B: gload_lds, pre-swizzled source
      int ld = (tid + c*256) * 16;
      int row = ld >> 7, b = ld & 127;
      int bs = b ^ ((row & 7) << 4);
      gload_lds16((const char*)W2bf + (size_t)(tn+row)*4096 + (kt*2 + bs),
                  (char*)Bs + (wave*64 + c*256)*16);
    }
    #pragma unroll
    for (int c = 0; c < 4; ++c) {           // A: reg-stage + BN + ReLU
      int ld = (tid + c*256) * 16;
      int row = ld >> 7, b = ld & 127;
      int kg = (kt - kOff) + (b >> 1);      // [0,256) LDS-local
      int4 hv = *(const int4*)((const char*)Hraw + (size_t)(tm+row)*4096 + kt*2 + b);
      f32x4 s0 = *(const f32x4*)(sLDS + kg), s1 = *(const f32x4*)(sLDS + kg + 4);
      f32x4 b0 = *(const f32x4*)(bLDS + kg), b1 = *(const f32x4*)(bLDS + kg + 4);
      u16* hp = (u16*)&hv;
      int4 ov; u16* op = (u16*)&ov;
      #pragma unroll
      for (int j = 0; j < 4; ++j)
        op[j]   = f2bf(fmaxf(fmaf(bf2f(hp[j]),   s0[j], b0[j]), 0.f));
      #pragma unroll
      for (int j = 0; j < 4; ++j)
        op[4+j] = f2bf(fmaxf(fmaf(bf2f(hp[4+j]), s1[j], b1[j]), 0.f));
      *(int4*)((char*)As + row*128 + (b ^ ((row & 7) << 4))) = ov;
    }
    __syncthreads();
    #pragma unroll
    for (int kk = 0; kk < 2; ++kk) {
      s16x8 af[4], bv[4];
      #pragma unroll
      for (int m = 0; m < 4; ++m) {
        int row = wr*64 + m*16 + r16;
        af[m] = *(const s16x8*)((const char*)As + row*128 +
                                ((kk*64 + g*16) ^ ((row & 7) << 4)));
      }
      #pragma unroll
      for (int n = 0; n < 4; ++n) {
        int row = wc*64 + n*16 + r16;
        bv[n] = *(const s16x8*)((const char*)Bs + row*128 +
                                ((kk*64 + g*16) ^ ((row & 7) << 4)));
      }
      #pragma unroll
      for (int m = 0; m < 4; ++m)
        #pragma unroll
        for (int n = 0; n < 4; ++n)
          acc[m][n] = mfma16(af[m], bv[n], acc[m][n]);
    }
    __syncthreads();
  }

  u16* Cfo = Zp + (size_t)blockIdx.z * (8192*128);
  #pragma unroll
  for (int m = 0; m < 4; ++m)
    #pragma unroll
    for (int n = 0; n < 4; ++n)
      #pragma unroll
      for (int r = 0; r < 4; ++r) {
        int row = tm + wr*64 + m*16 + g*4 + r;
        int col = tn + wc*64 + n*16 + r16;
        Cfo[(size_t)row*128 + col] = f2bf(acc[m][n][r]);
      }
}

// ------- sum 8 bf16 K-split partials + L2-normalize rows -> bf16 ------------------
__global__ __launch_bounds__(256)
void normk(const u16* __restrict__ Zp, u16* __restrict__ Zb)
{
  int row = blockIdx.x * 16 + (threadIdx.x >> 4);
  int l16 = threadIdx.x & 15;
  size_t off = (size_t)row*128 + l16*8;
  f32x4 v0 = {0.f,0.f,0.f,0.f}, v1 = {0.f,0.f,0.f,0.f};
  #pragma unroll
  for (int s = 0; s < 8; ++s) {
    int4 pv = *(const int4*)(Zp + (size_t)s*1048576 + off);
    const u16* pp = (const u16*)&pv;
    v0[0] += bf2f(pp[0]); v0[1] += bf2f(pp[1]); v0[2] += bf2f(pp[2]); v0[3] += bf2f(pp[3]);
    v1[0] += bf2f(pp[4]); v1[1] += bf2f(pp[5]); v1[2] += bf2f(pp[6]); v1[3] += bf2f(pp[7]);
  }
  float ss = v0[0]*v0[0] + v0[1]*v0[1] + v0[2]*v0[2] + v0[3]*v0[3]
           + v1[0]*v1[0] + v1[1]*v1[1] + v1[2]*v1[2] + v1[3]*v1[3];
  #pragma unroll
  for (int o = 1; o < 16; o <<= 1) ss += __shfl_xor(ss, o);
  float rs = rsqrtf(ss);
  rs = rs * (1.5f - 0.5f * ss * rs * rs);
  int4 ov; u16* op = (u16*)&ov;
  op[0]=f2bf(v0[0]*rs); op[1]=f2bf(v0[1]*rs); op[2]=f2bf(v0[2]*rs); op[3]=f2bf(v0[3]*rs);
  op[4]=f2bf(v1[0]*rs); op[5]=f2bf(v1[1]*rs); op[6]=f2bf(v1[2]*rs); op[7]=f2bf(v1[3]*rs);
  *(int4*)((char*)Zb + off*2) = ov;
}

// --- fused sim + fixed-max LSE + weighted score + weight-sum (64 rows/block) -------
#define LOAD_COL(DC, DL, IT) do {                                                  \
  int jr_ = colBase + (IT)*16;                                                     \
  const char* zcp_ = (const char*)Zb + (size_t)(jr_ + r16)*256 + g*16;             \
  DC[0] = *(const s16x8*)(zcp_);        DC[1] = *(const s16x8*)(zcp_ +  64);       \
  DC[2] = *(const s16x8*)(zcp_ + 128);  DC[3] = *(const s16x8*)(zcp_ + 192);       \
  DL = *(const f32x4*)(labels + ((jr_ & 4095) + g*4));                             \
} while (0)

#define LBODY(CC, CL, IT) do {                                                     \
  int jrow_ = colBase + (IT)*16;                                                   \
  f32x4 aacc[4] = {};                                                              \
  _Pragma("unroll")                                                                \
  for (int kk = 0; kk < 4; ++kk) {                                                 \
    _Pragma("unroll")                                                              \
    for (int is = 0; is < 4; ++is)                                                 \
      aacc[is] = mfma16(CC[kk], zr[is][kk], aacc[is]);                             \
  }                                                                                \
  _Pragma("unroll")                                                                \
  for (int r = 0; r < 4; ++r) {                                                    \
    int j = jrow_ + g*4 + r;                                                       \
    _Pragma("unroll")                                                              \
    for (int is = 0; is < 4; ++is) {                                               \
      float d = aacc[is][r];                                                       \
      bool diag = (rowBase + is*16 + r16) == j;                                    \
      float e  = __expf(fmaf(d, 10.f, -10.f));                                     \
      float dl = li[is] - CL[r];                                                   \
      float w  = __expf(-GAMMA_C * dl * dl);                                       \
      e = diag ? 0.f : e;                                                          \
      w = diag ? 0.f : w;                                                          \
      l[is] += e;                                                                  \
      wS[is] += w;                                                                 \
      wA[is] = fmaf(w, d, wA[is]);                                                 \
    }                                                                              \
  }                                                                                \
} while (0)

__global__ __launch_bounds__(64)
void lossk(const u16* __restrict__ Zb, const float* __restrict__ labels,
           float* __restrict__ lacc, float* __restrict__ wacc,
           float* __restrict__ sacc)
{
  const int lane = threadIdx.x & 63;
  const int g = lane >> 4, r16 = lane & 15;
  const int split = blockIdx.x;
  const int rowBase = blockIdx.y * 64;
  const int colBase = split * 512;

  s16x8 zr[4][4];
  float li[4];
  #pragma unroll
  for (int is = 0; is < 4; ++is) {
    int i = rowBase + is*16 + r16;
    li[is] = labels[i & 4095];
    #pragma unroll
    for (int kk = 0; kk < 4; ++kk)
      zr[is][kk] = *(const s16x8*)((const char*)Zb + (size_t)i*256 + kk*64 + g*16);
  }

  float l[4]  = {0.f, 0.f, 0.f, 0.f};
  float wA[4] = {0.f, 0.f, 0.f, 0.f};
  float wS[4] = {0.f, 0.f, 0.f, 0.f};

  s16x8 cA[4], cB[4];
  f32x4 lA, lB;
  LOAD_COL(cA, lA, 0);
  for (int it = 0; it < 32; it += 2) {      // 32 col-tiles of 16
    LOAD_COL(cB, lB, it + 1);
    LBODY(cA, lA, it);
    if (it + 2 < 32) LOAD_COL(cA, lA, it + 2);
    LBODY(cB, lB, it + 1);
  }

  #pragma unroll
  for (int is = 0; is < 4; ++is) {
    float lv = l[is], wv = wA[is], sv = wS[is];
    lv += __shfl_xor(lv, 16); lv += __shfl_xor(lv, 32);
    wv += __shfl_xor(wv, 16); wv += __shfl_xor(wv, 32);
    sv += __shfl_xor(sv, 16); sv += __shfl_xor(sv, 32);
    if (g == 0) {
      int i = rowBase + is*16 + r16;
      atomicAdd(&lacc[i], lv);
      atomicAdd(&wacc[i], wv);
      atomicAdd(&sacc[i], sv);
    }
  }
}

// ---------------- per-row loss + final reduce ----------------
__global__ __launch_bounds__(256)
void finalk(const float* __restrict__ lacc, const float* __restrict__ wacc,
            const float* __restrict__ sacc, float* __restrict__ out)
{
  __shared__ float red[256];
  float a = 0.f;
  for (int i = threadIdx.x; i < 8192; i += 256)
    a += wacc[i] * 10.f / sacc[i] - (10.f + logf(lacc[i]));
  red[threadIdx.x] = a;
  __syncthreads();
  for (int off = 128; off > 0; off >>= 1) {
    if (threadIdx.x < off) red[threadIdx.x] += red[threadIdx.x + off];
    __syncthreads();
  }
  if (threadIdx.x == 0) out[0] = -red[0] * (1.f/4096.f);
}

extern "C" void kernel_launch(void* const* d_in, const int* in_sizes, int n_in,
                              void* d_out, int out_size, void* d_ws, size_t ws_size,
                              hipStream_t stream) {
  const float* y1     = (const float*)d_in[0];
  const float* y2     = (const float*)d_in[1];
  const float* labels = (const float*)d_in[2];
  const float* W1     = (const float*)d_in[3];
  const float* bng    = (const float*)d_in[4];
  const float* bnb    = (const float*)d_in[5];
  const float* W2     = (const float*)d_in[6];
  float* out = (float*)d_out;
  char* ws = (char*)d_ws;

  // layout (peak 76,152,832 B) — r11 proven:
  u16*   Ybf    = (u16*)(ws);                    // [0, 32M)      dead after gemm1
  u16*   W1bf   = (u16*)(ws + 33554432);         // [32M, 40M)    dead after gemm1
  float* zbuf   = (float*)(ws + 41943040);       // 128KB ZBUF (zeroed by castall)
  float* psum   = (float*)(ws + 41943040);       //   16KB
  float* psumsq = (float*)(ws + 41959424);       //   16KB
  float* lacc   = (float*)(ws + 41975808);       //   32KB
  float* wacc   = (float*)(ws + 42008576);       //   32KB
  float* sacc   = (float*)(ws + 42041344);       //   32KB -> ends 42,074,112
  u16*   W2bf   = (u16*)(ws + 42074112);         // 512KB -> ends 42,598,400
  u16*   Hraw   = (u16*)(ws + 42598400);         // 32MB  -> ends 76,152,832
  // post-gemm1 overlays (dead Ybf/W1bf):
  u16*   Zp     = (u16*)(ws + 32768);            // 16MB [8][8192][128] bf16
  u16*   Zbf    = (u16*)(ws + 33587200);         // 2MB -> ends 35,684,352

  castall<<<10400, 256, 0, stream>>>(y1, y2, W1, W2, Ybf, W1bf, W2bf, zbuf);
  gemm1<<<256, 512, 0, stream>>>(Ybf, W1bf, Hraw, psum, psumsq);
  gemm2f<<<dim3(1,64,8), 256, 0, stream>>>(Hraw, W2bf, psum, psumsq, bng, bnb, Zp, 256);
  normk<<<512, 256, 0, stream>>>(Zp, Zbf);
  lossk<<<dim3(NSPLIT, 128), 64, 0, stream>>>(Zbf, labels, lacc, wacc, sacc);
  finalk<<<1, 256, 0, stream>>>(lacc, wacc, sacc, out);
}

// Round 14
// 149.924 us; speedup vs baseline: 1.5217x; 1.0230x over previous
//
#include <hip/hip_runtime.h>

typedef unsigned short u16;
typedef unsigned int   u32;
typedef float  f32x4  __attribute__((ext_vector_type(4)));
typedef short  s16x8  __attribute__((ext_vector_type(8)));
typedef __bf16 bf16x8 __attribute__((ext_vector_type(8)));

#define GAMMA_C 0.02f     // 1/(2*sigma^2), sigma=5
#define NSPLIT 16

__device__ __forceinline__ float bf2f(u16 h) {
  union { u32 u; float f; } c; c.u = ((u32)h) << 16; return c.f;
}
__device__ __forceinline__ u16 f2bf(float f) {
  union { float f; u32 u; } c; c.f = f;
  u32 u = c.u;
  return (u16)((u + 0x7fffu + ((u >> 16) & 1u)) >> 16);
}
__device__ __forceinline__ f32x4 mfma16(s16x8 a, s16x8 b, f32x4 c) {
  union { s16x8 s; bf16x8 b; } ua, ub; ua.s = a; ub.s = b;
  return __builtin_amdgcn_mfma_f32_16x16x32_bf16(ua.b, ub.b, c, 0, 0, 0);
}
__device__ __forceinline__ void gload_lds16(const void* g, void* l) {
  __builtin_amdgcn_global_load_lds(
      (__attribute__((address_space(1))) const void*)g,
      (__attribute__((address_space(3))) void*)l, 16, 0, 0);
}

// -- f32 -> bf16 casts (y1, y2, W1, W2) + zero ZBUF (psum/psumsq/lacc/wacc/sacc) ----
__global__ __launch_bounds__(256)
void castall(const float* __restrict__ y1, const float* __restrict__ y2,
             const float* __restrict__ W1, const float* __restrict__ W2,
             u16* __restrict__ Ybf, u16* __restrict__ W1bf,
             u16* __restrict__ W2bf, float* __restrict__ zbuf) {
  int b = blockIdx.x;
  if (b >= 10368) {                    // zero 128KB (32 blocks x 4KB)
    int i = ((b - 10368) * 256 + threadIdx.x) * 4;
    *(float4*)(zbuf + i) = make_float4(0.f, 0.f, 0.f, 0.f);
    return;
  }
  const float* src; u16* dst; int off;
  if (b < 4096)       { src = y1; dst = Ybf;           off = b; }
  else if (b < 8192)  { src = y2; dst = Ybf + 8388608; off = b - 4096; }
  else if (b < 10240) { src = W1; dst = W1bf;          off = b - 8192; }
  else                { src = W2; dst = W2bf;          off = b - 10240; }
  int idx = (off * 256 + threadIdx.x) * 8;
  float4 a = *(const float4*)(src + idx);
  float4 c = *(const float4*)(src + idx + 4);
  int4 ov; u16* op = (u16*)&ov;
  op[0]=f2bf(a.x); op[1]=f2bf(a.y); op[2]=f2bf(a.z); op[3]=f2bf(a.w);
  op[4]=f2bf(c.x); op[5]=f2bf(c.y); op[6]=f2bf(c.z); op[7]=f2bf(c.w);
  *(int4*)(dst + idx) = ov;
}

// ===== gemm1 v6: r13 quarters/counted-vmcnt schedule, ONE barrier per phase =====
// BAR#2 removed: all STAGE targets are >=2 BAR-segments from their last reader;
// all frag reads are >=1 BAR downstream of the staging waves' VMW6.
#define SWZ1(row) (((row) & 7) << 4)
#define BAR() __builtin_amdgcn_s_barrier()
#define VMW0() asm volatile("s_waitcnt vmcnt(0)" ::: "memory")
#define VMW6() asm volatile("s_waitcnt vmcnt(6)" ::: "memory")

#define STAGE_Q(BUF, KT, CQ) do {                                                  \
  int e_ = tid + (CQ)*512; int row_ = e_ >> 3; int b_ = (e_ & 7) * 16;             \
  int bs_ = b_ ^ SWZ1(row_);                                                       \
  gload_lds16((const char*)A + (size_t)(tm+row_)*4096 + (KT)*2 + bs_,              \
              (char*)&As[BUF][0] + ((CQ)*512 + wave*64)*16);                       \
  gload_lds16((const char*)B + (size_t)(tn+row_)*4096 + (KT)*2 + bs_,              \
              (char*)&Bs[BUF][0] + ((CQ)*512 + wave*64)*16);                       \
} while (0)

#define LDA(DST, BUF, MH) do {                                                     \
  _Pragma("unroll")                                                                \
  for (int m_ = 0; m_ < 4; ++m_)                                                   \
    _Pragma("unroll")                                                              \
    for (int kk_ = 0; kk_ < 2; ++kk_) {                                            \
      int arow_ = wr*16 + ((MH)*4 + m_)*32 + r16;                                  \
      DST[m_*2 + kk_] = *(const s16x8*)((const char*)&As[BUF][0] + arow_*128 +     \
                          ((kk_*64 + g*16) ^ SWZ1(arow_)));                        \
    }                                                                              \
} while (0)

#define LDB(DST, BUF, NH) do {                                                     \
  _Pragma("unroll")                                                                \
  for (int n_ = 0; n_ < 2; ++n_)                                                   \
    _Pragma("unroll")                                                              \
    for (int kk_ = 0; kk_ < 2; ++kk_) {                                            \
      int brow_ = wc*16 + ((NH)*2 + n_)*64 + r16;                                  \
      DST[n_*2 + kk_] = *(const s16x8*)((const char*)&Bs[BUF][0] + brow_*128 +     \
                          ((kk_*64 + g*16) ^ SWZ1(brow_)));                        \
    }                                                                              \
} while (0)

#define MMQ(AF, MH, NH) do {                                                       \
  __builtin_amdgcn_s_setprio(1);                                                   \
  _Pragma("unroll")                                                                \
  for (int m_ = 0; m_ < 4; ++m_)                                                   \
    _Pragma("unroll")                                                              \
    for (int n_ = 0; n_ < 2; ++n_)                                                 \
      _Pragma("unroll")                                                            \
      for (int kk_ = 0; kk_ < 2; ++kk_)                                            \
        acc[(MH)*4 + m_][(NH)*2 + n_] =                                            \
          mfma16(AF[m_*2 + kk_], bv[n_*2 + kk_], acc[(MH)*4 + m_][(NH)*2 + n_]);   \
  __builtin_amdgcn_s_setprio(0);                                                   \
} while (0)

__global__ __launch_bounds__(512, 2)
void gemm1(const u16* __restrict__ A, const u16* __restrict__ B,
           u16* __restrict__ C, float* __restrict__ psum, float* __restrict__ psumsq)
{
  __shared__ u16 As[2][256*64];
  __shared__ u16 Bs[2][256*64];
  const int tid = threadIdx.x;
  const int lane = tid & 63, wave = tid >> 6;   // 8 waves
  const int wr = wave >> 2, wc = wave & 3;      // 2 x 4
  const int g = lane >> 4, r16 = lane & 15;
  const int lin = blockIdx.x;                   // 256 blocks, 256 % 8 == 0
  const int wgid = (lin & 7) * 32 + (lin >> 3); // XCD owns 32 contiguous wgids
  const int by = wgid >> 3, bx = wgid & 7;
  const int tm = by * 256, tn = bx * 256;

  f32x4 acc[8][4] = {};
  s16x8 af0[8], af1[8], bv[4];

  // prologue: tile0 full (8 loads) + Q1,Q2 of tile1 (4 loads); retire tile0
  STAGE_Q(0, 0, 0); STAGE_Q(0, 0, 1); STAGE_Q(0, 0, 2); STAGE_Q(0, 0, 3);
  STAGE_Q(1, 64, 0); STAGE_Q(1, 64, 1);
  asm volatile("s_waitcnt vmcnt(4)" ::: "memory");
  BAR();

  for (int t = 0; t < 32; ++t) {
    const int cur = t & 1, nxt = cur ^ 1;
    const int ktn = (t + 1) * 64, ktn2 = (t + 2) * 64;
    // P1: read q1 frags (Q1,Q2 cur: confirmed at P4(t-1)); stage Q3(t+1); retire Q4(t)
    LDA(af0, cur, 0);  LDB(bv, cur, 0);
    if (t < 31) { STAGE_Q(nxt, ktn, 2); VMW6(); }
    BAR();  MMQ(af0, 0, 0);
    // P2: read q2 frags (Q3,Q4 cur confirmed); stage Q4(t+1)
    LDA(af1, cur, 1);
    if (t < 31) STAGE_Q(nxt, ktn, 3);
    BAR();  MMQ(af1, 1, 0);
    // P3: read q3 frags; stage Q1(t+2) into cur (rows 0-63 dead since P1)
    LDB(bv, cur, 1);
    if (t < 30) STAGE_Q(cur, ktn2, 0);
    BAR();  MMQ(af1, 1, 1);
    // P4: stage Q2(t+2); retire Q1-Q3(t+1) (t=30: full drain for tail)
    if (t < 30)      { STAGE_Q(cur, ktn2, 1); VMW6(); }
    else if (t == 30) VMW0();
    BAR();  MMQ(af0, 0, 1);
  }

  // epilogue: C store (bf16); C/D frag: col=lane&15, row=(lane>>4)*4+reg
  #pragma unroll
  for (int m = 0; m < 8; ++m)
    #pragma unroll
    for (int n = 0; n < 4; ++n)
      #pragma unroll
      for (int r = 0; r < 4; ++r) {
        int row = tm + wr*16 + m*32 + g*4 + r;
        int col = tn + wc*16 + n*64 + r16;
        C[(size_t)row*2048 + col] = f2bf(acc[m][n][r]);
      }

  // BN column partials over this block's 256 rows -> one atomicAdd per column
  __syncthreads();
  float* sred  = (float*)&As[0][0];   // [2][256]
  float* ssred = sred + 512;
  #pragma unroll
  for (int n = 0; n < 4; ++n) {
    float s = 0.f, ss = 0.f;
    #pragma unroll
    for (int m = 0; m < 8; ++m)
      #pragma unroll
      for (int r = 0; r < 4; ++r) { float v = acc[m][n][r]; s += v; ss = fmaf(v, v, ss); }
    s  += __shfl_xor(s, 16);  s  += __shfl_xor(s, 32);
    ss += __shfl_xor(ss, 16); ss += __shfl_xor(ss, 32);
    if (g == 0) {
      int lc = wc*16 + n*64 + r16;
      sred [wr*256 + lc] = s;
      ssred[wr*256 + lc] = ss;
    }
  }
  __syncthreads();
  if (tid < 256) {
    int half = tm >> 12;
    atomicAdd(&psum  [half*2048 + tn + tid], sred [tid] + sred [256 + tid]);
    atomicAdd(&psumsq[half*2048 + tn + tid], ssred[tid] + ssred[256 + tid]);
  }
}

// ======= gemm2f: Z-partials = relu(BN(H)) * W2^T, split-K, bf16 partial out; ======
// inline BN finalize from psum/psumsq (r11 proven — NO fences, NO counters).
__global__ __launch_bounds__(256)
void gemm2f(const u16* __restrict__ Hraw, const u16* __restrict__ W2bf,
            const float* __restrict__ psum, const float* __restrict__ psumsq,
            const float* __restrict__ gam, const float* __restrict__ bet,
            u16* __restrict__ Zp, int kLen)
{
  __shared__ u16 As[128*64];
  __shared__ u16 Bs[128*64];
  __shared__ float sLDS[256], bLDS[256];
  const int tid = threadIdx.x;
  const int lane = tid & 63, wave = tid >> 6;
  const int wr = wave >> 1, wc = wave & 1;
  const int g = lane >> 4, r16 = lane & 15;
  const int tm = blockIdx.y * 128, tn = blockIdx.x * 128;
  const int kOff = blockIdx.z * kLen;
  const int half = tm >> 12;

  {                                         // inline BN finalize for [kOff, kOff+256)
    int c = half*2048 + kOff + tid;
    float mu  = psum[c] * (1.f/4096.f);
    float var = fmaxf(psumsq[c] * (1.f/4096.f) - mu*mu, 0.f);
    float sc = gam[kOff + tid] * rsqrtf(var + 1e-5f);
    sLDS[tid] = sc;
    bLDS[tid] = bet[kOff + tid] - mu * sc;
  }
  __syncthreads();

  f32x4 acc[4][4] = {};

  for (int kt = kOff; kt < kOff + kLen; kt += 64) {
    #pragma unroll
    for (int c = 0; c < 4; ++c) {           // B: gload_lds, pre-swizzled source
      int ld = (tid + c*256) * 16;
      int row = ld >> 7, b = ld & 127;
      int bs = b ^ ((row & 7) << 4);
      gload_lds16((const char*)W2bf + (size_t)(tn+row)*4096 + (kt*2 + bs),
                  (char*)Bs + (wave*64 + c*256)*16);
    }
    #pragma unroll
    for (int c = 0; c < 4; ++c) {           // A: reg-stage + BN + ReLU
      int ld = (tid + c*256) * 16;
      int row = ld >> 7, b = ld & 127;
      int kg = (kt - kOff) + (b >> 1);      // [0,256) LDS-local
      int4 hv = *(const int4*)((const char*)Hraw + (size_t)(tm+row)*4096 + kt*2 + b);
      f32x4 s0 = *(const f32x4*)(sLDS + kg), s1 = *(const f32x4*)(sLDS + kg + 4);
      f32x4 b0 = *(const f32x4*)(bLDS + kg), b1 = *(const f32x4*)(bLDS + kg + 4);
      u16* hp = (u16*)&hv;
      int4 ov; u16* op = (u16*)&ov;
      #pragma unroll
      for (int j = 0; j < 4; ++j)
        op[j]   = f2bf(fmaxf(fmaf(bf2f(hp[j]),   s0[j], b0[j]), 0.f));
      #pragma unroll
      for (int j = 0; j < 4; ++j)
        op[4+j] = f2bf(fmaxf(fmaf(bf2f(hp[4+j]), s1[j], b1[j]), 0.f));
      *(int4*)((char*)As + row*128 + (b ^ ((row & 7) << 4))) = ov;
    }
    __syncthreads();
    #pragma unroll
    for (int kk = 0; kk < 2; ++kk) {
      s16x8 af[4], bv[4];
      #pragma unroll
      for (int m = 0; m < 4; ++m) {
        int row = wr*64 + m*16 + r16;
        af[m] = *(const s16x8*)((const char*)As + row*128 +
                                ((kk*64 + g*16) ^ ((row & 7) << 4)));
      }
      #pragma unroll
      for (int n = 0; n < 4; ++n) {
        int row = wc*64 + n*16 + r16;
        bv[n] = *(const s16x8*)((const char*)Bs + row*128 +
                                ((kk*64 + g*16) ^ ((row & 7) << 4)));
      }
      #pragma unroll
      for (int m = 0; m < 4; ++m)
        #pragma unroll
        for (int n = 0; n < 4; ++n)
          acc[m][n] = mfma16(af[m], bv[n], acc[m][n]);
    }
    __syncthreads();
  }

  u16* Cfo = Zp + (size_t)blockIdx.z * (8192*128);
  #pragma unroll
  for (int m = 0; m < 4; ++m)
    #pragma unroll
    for (int n = 0; n < 4; ++n)
      #pragma unroll
      for (int r = 0; r < 4; ++r) {
        int row = tm + wr*64 + m*16 + g*4 + r;
        int col = tn + wc*64 + n*16 + r16;
        Cfo[(size_t)row*128 + col] = f2bf(acc[m][n][r]);
      }
}

// ------- sum 8 bf16 K-split partials + L2-normalize rows -> bf16 ------------------
__global__ __launch_bounds__(256)
void normk(const u16* __restrict__ Zp, u16* __restrict__ Zb)
{
  int row = blockIdx.x * 16 + (threadIdx.x >> 4);
  int l16 = threadIdx.x & 15;
  size_t off = (size_t)row*128 + l16*8;
  f32x4 v0 = {0.f,0.f,0.f,0.f}, v1 = {0.f,0.f,0.f,0.f};
  #pragma unroll
  for (int s = 0; s < 8; ++s) {
    int4 pv = *(const int4*)(Zp + (size_t)s*1048576 + off);
    const u16* pp = (const u16*)&pv;
    v0[0] += bf2f(pp[0]); v0[1] += bf2f(pp[1]); v0[2] += bf2f(pp[2]); v0[3] += bf2f(pp[3]);
    v1[0] += bf2f(pp[4]); v1[1] += bf2f(pp[5]); v1[2] += bf2f(pp[6]); v1[3] += bf2f(pp[7]);
  }
  float ss = v0[0]*v0[0] + v0[1]*v0[1] + v0[2]*v0[2] + v0[3]*v0[3]
           + v1[0]*v1[0] + v1[1]*v1[1] + v1[2]*v1[2] + v1[3]*v1[3];
  #pragma unroll
  for (int o = 1; o < 16; o <<= 1) ss += __shfl_xor(ss, o);
  float rs = rsqrtf(ss);
  rs = rs * (1.5f - 0.5f * ss * rs * rs);
  int4 ov; u16* op = (u16*)&ov;
  op[0]=f2bf(v0[0]*rs); op[1]=f2bf(v0[1]*rs); op[2]=f2bf(v0[2]*rs); op[3]=f2bf(v0[3]*rs);
  op[4]=f2bf(v1[0]*rs); op[5]=f2bf(v1[1]*rs); op[6]=f2bf(v1[2]*rs); op[7]=f2bf(v1[3]*rs);
  *(int4*)((char*)Zb + off*2) = ov;
}

// --- fused sim + fixed-max LSE + weighted score + weight-sum (64 rows/block) -------
#define LOAD_COL(DC, DL, IT) do {                                                  \
  int jr_ = colBase + (IT)*16;                                                     \
  const char* zcp_ = (const char*)Zb + (size_t)(jr_ + r16)*256 + g*16;             \
  DC[0] = *(const s16x8*)(zcp_);        DC[1] = *(const s16x8*)(zcp_ +  64);       \
  DC[2] = *(const s16x8*)(zcp_ + 128);  DC[3] = *(const s16x8*)(zcp_ + 192);       \
  DL = *(const f32x4*)(labels + ((jr_ & 4095) + g*4));                             \
} while (0)

#define LBODY(CC, CL, IT) do {                                                     \
  int jrow_ = colBase + (IT)*16;                                                   \
  f32x4 aacc[4] = {};                                                              \
  _Pragma("unroll")                                                                \
  for (int kk = 0; kk < 4; ++kk) {                                                 \
    _Pragma("unroll")                                                              \
    for (int is = 0; is < 4; ++is)                                                 \
      aacc[is] = mfma16(CC[kk], zr[is][kk], aacc[is]);                             \
  }                                                                                \
  _Pragma("unroll")                                                                \
  for (int r = 0; r < 4; ++r) {                                                    \
    int j = jrow_ + g*4 + r;                                                       \
    _Pragma("unroll")                                                              \
    for (int is = 0; is < 4; ++is) {                                               \
      float d = aacc[is][r];                                                       \
      bool diag = (rowBase + is*16 + r16) == j;                                    \
      float e  = __expf(fmaf(d, 10.f, -10.f));                                     \
      float dl = li[is] - CL[r];                                                   \
      float w  = __expf(-GAMMA_C * dl * dl);                                       \
      e = diag ? 0.f : e;                                                          \
      w = diag ? 0.f : w;                                                          \
      l[is] += e;                                                                  \
      wS[is] += w;                                                                 \
      wA[is] = fmaf(w, d, wA[is]);                                                 \
    }                                                                              \
  }                                                                                \
} while (0)

__global__ __launch_bounds__(64)
void lossk(const u16* __restrict__ Zb, const float* __restrict__ labels,
           float* __restrict__ lacc, float* __restrict__ wacc,
           float* __restrict__ sacc)
{
  const int lane = threadIdx.x & 63;
  const int g = lane >> 4, r16 = lane & 15;
  const int split = blockIdx.x;
  const int rowBase = blockIdx.y * 64;
  const int colBase = split * 512;

  s16x8 zr[4][4];
  float li[4];
  #pragma unroll
  for (int is = 0; is < 4; ++is) {
    int i = rowBase + is*16 + r16;
    li[is] = labels[i & 4095];
    #pragma unroll
    for (int kk = 0; kk < 4; ++kk)
      zr[is][kk] = *(const s16x8*)((const char*)Zb + (size_t)i*256 + kk*64 + g*16);
  }

  float l[4]  = {0.f, 0.f, 0.f, 0.f};
  float wA[4] = {0.f, 0.f, 0.f, 0.f};
  float wS[4] = {0.f, 0.f, 0.f, 0.f};

  s16x8 cA[4], cB[4];
  f32x4 lA, lB;
  LOAD_COL(cA, lA, 0);
  for (int it = 0; it < 32; it += 2) {      // 32 col-tiles of 16
    LOAD_COL(cB, lB, it + 1);
    LBODY(cA, lA, it);
    if (it + 2 < 32) LOAD_COL(cA, lA, it + 2);
    LBODY(cB, lB, it + 1);
  }

  #pragma unroll
  for (int is = 0; is < 4; ++is) {
    float lv = l[is], wv = wA[is], sv = wS[is];
    lv += __shfl_xor(lv, 16); lv += __shfl_xor(lv, 32);
    wv += __shfl_xor(wv, 16); wv += __shfl_xor(wv, 32);
    sv += __shfl_xor(sv, 16); sv += __shfl_xor(sv, 32);
    if (g == 0) {
      int i = rowBase + is*16 + r16;
      atomicAdd(&lacc[i], lv);
      atomicAdd(&wacc[i], wv);
      atomicAdd(&sacc[i], sv);
    }
  }
}

// ---------------- per-row loss + final reduce ----------------
__global__ __launch_bounds__(256)
void finalk(const float* __restrict__ lacc, const float* __restrict__ wacc,
            const float* __restrict__ sacc, float* __restrict__ out)
{
  __shared__ float red[256];
  float a = 0.f;
  for (int i = threadIdx.x; i < 8192; i += 256)
    a += wacc[i] * 10.f / sacc[i] - (10.f + logf(lacc[i]));
  red[threadIdx.x] = a;
  __syncthreads();
  for (int off = 128; off > 0; off >>= 1) {
    if (threadIdx.x < off) red[threadIdx.x] += red[threadIdx.x + off];
    __syncthreads();
  }
  if (threadIdx.x == 0) out[0] = -red[0] * (1.f/4096.f);
}

extern "C" void kernel_launch(void* const* d_in, const int* in_sizes, int n_in,
                              void* d_out, int out_size, void* d_ws, size_t ws_size,
                              hipStream_t stream) {
  const float* y1     = (const float*)d_in[0];
  const float* y2     = (const float*)d_in[1];
  const float* labels = (const float*)d_in[2];
  const float* W1     = (const float*)d_in[3];
  const float* bng    = (const float*)d_in[4];
  const float* bnb    = (const float*)d_in[5];
  const float* W2     = (const float*)d_in[6];
  float* out = (float*)d_out;
  char* ws = (char*)d_ws;

  // layout (peak 76,152,832 B) — r11 proven:
  u16*   Ybf    = (u16*)(ws);                    // [0, 32M)      dead after gemm1
  u16*   W1bf   = (u16*)(ws + 33554432);         // [32M, 40M)    dead after gemm1
  float* zbuf   = (float*)(ws + 41943040);       // 128KB ZBUF (zeroed by castall)
  float* psum   = (float*)(ws + 41943040);       //   16KB
  float* psumsq = (float*)(ws + 41959424);       //   16KB
  float* lacc   = (float*)(ws + 41975808);       //   32KB
  float* wacc   = (float*)(ws + 42008576);       //   32KB
  float* sacc   = (float*)(ws + 42041344);       //   32KB -> ends 42,074,112
  u16*   W2bf   = (u16*)(ws + 42074112);         // 512KB -> ends 42,598,400
  u16*   Hraw   = (u16*)(ws + 42598400);         // 32MB  -> ends 76,152,832
  // post-gemm1 overlays (dead Ybf/W1bf):
  u16*   Zp     = (u16*)(ws + 32768);            // 16MB [8][8192][128] bf16
  u16*   Zbf    = (u16*)(ws + 33587200);         // 2MB -> ends 35,684,352

  castall<<<10400, 256, 0, stream>>>(y1, y2, W1, W2, Ybf, W1bf, W2bf, zbuf);
  gemm1<<<256, 512, 0, stream>>>(Ybf, W1bf, Hraw, psum, psumsq);
  gemm2f<<<dim3(1,64,8), 256, 0, stream>>>(Hraw, W2bf, psum, psumsq, bng, bnb, Zp, 256);
  normk<<<512, 256, 0, stream>>>(Zp, Zbf);
  lossk<<<dim3(NSPLIT, 128), 64, 0, stream>>>(Zbf, labels, lacc, wacc, sacc);
  finalk<<<1, 256, 0, stream>>>(lacc, wacc, sacc, out);
}